// Round 1
// baseline (109.829 us; speedup 1.0000x reference)
//
#include <hip/hip_runtime.h>

// Problem constants (fixed by setup_inputs): B=2, N=96, L=128
#define NANG 96
#define LDIM 128
#define NB   2

// Block: 256 threads, handles 4 output pixels (r,q).
//   tid>>6  = sub-pixel within block (0..3)
//   lane&63: b = lane>>5 (0..1), zq = lane&31 -> z = 4*zq (float4 along z)
// Geometry (wA, wB, xc0*L, xc1*L) per (pixel, angle) staged in LDS.
__global__ __launch_bounds__(256)
void backproj_kernel(const float* __restrict__ image,   // [B, N, L, L]
                     const float* __restrict__ angles,  // [N]
                     float* __restrict__ out)           // [B, L, L, L]
{
    __shared__ float4 geo[4 * NANG];

    const int tid = threadIdx.x;
    const int p0 = blockIdx.x * 4;   // first pixel id of this block

    // ---- Phase 1: geometry for 4 pixels x 96 angles ----
    for (int e = tid; e < 4 * NANG; e += 256) {
        const int sub = e / NANG;          // 0..3
        const int n   = e - sub * NANG;    // angle index
        const int p   = p0 + sub;
        const int r   = p >> 7;            // Lx (row) index
        const int q   = p & 127;           // Ly (col) index

        const float ang = angles[n];
        const float phi = 270.0f - ang;
        const float th  = phi * 0.017453292519943295f;  // deg->rad
        float s, c;
        sincosf(th, &s, &c);

        const float xr = (float)q - 63.5f;
        const float yr = (float)r - 63.5f;
        const float sx =  c * xr + s * yr + 63.5f;
        const float sy = -s * xr + c * yr + 63.5f;

        const float x0f = floorf(sx);
        const float y0f = floorf(sy);
        const float wx = sx - x0f;
        const float wy = sy - y0f;
        const int x0 = (int)x0f;
        const int y0 = (int)y0f;

        const float vy0 = (y0 >= 0 && y0 < LDIM)         ? 1.0f : 0.0f;
        const float vy1 = (y0 + 1 >= 0 && y0 + 1 < LDIM) ? 1.0f : 0.0f;
        const float vx0 = (x0 >= 0 && x0 < LDIM)         ? 1.0f : 0.0f;
        const float vx1 = (x0 + 1 >= 0 && x0 + 1 < LDIM) ? 1.0f : 0.0f;

        const float ycomb = vy0 * (1.0f - wy) + vy1 * wy;
        const float wA = (1.0f - wx) * ycomb * vx0;
        const float wB = wx * ycomb * vx1;

        const int xc0 = min(max(x0, 0), LDIM - 1);
        const int xc1 = min(max(x0 + 1, 0), LDIM - 1);

        geo[e] = make_float4(wA, wB,
                             __int_as_float(xc0 * LDIM),
                             __int_as_float(xc1 * LDIM));
    }
    __syncthreads();

    // ---- Phase 2: accumulate over angles ----
    const int sub  = tid >> 6;
    const int lane = tid & 63;
    const int b    = lane >> 5;
    const int z    = (lane & 31) * 4;
    const int p    = p0 + sub;
    const int r    = p >> 7;
    const int q    = p & 127;

    const float* imgb = image + (size_t)b * NANG * LDIM * LDIM + z;
    const float4* __restrict__ gbase = &geo[sub * NANG];

    float4 acc = make_float4(0.f, 0.f, 0.f, 0.f);
    float nacc = 0.f;

    #pragma unroll 4
    for (int n = 0; n < NANG; ++n) {
        const float4 g = gbase[n];
        const int o0 = __float_as_int(g.z);
        const int o1 = __float_as_int(g.w);
        const float* rowbase = imgb + n * (LDIM * LDIM);
        const float4 v0 = *(const float4*)(rowbase + o0);
        const float4 v1 = *(const float4*)(rowbase + o1);
        acc.x = fmaf(g.x, v0.x, fmaf(g.y, v1.x, acc.x));
        acc.y = fmaf(g.x, v0.y, fmaf(g.y, v1.y, acc.y));
        acc.z = fmaf(g.x, v0.z, fmaf(g.y, v1.z, acc.z));
        acc.w = fmaf(g.x, v0.w, fmaf(g.y, v1.w, acc.w));
        nacc += g.x + g.y;
    }

    const float inv = 1.0f / (nacc + 1e-11f);
    float4 res;
    res.x = acc.x * inv;
    res.y = acc.y * inv;
    res.z = acc.z * inv;
    res.w = acc.w * inv;

    *(float4*)(out + ((((size_t)b * LDIM + r) * LDIM + q) * LDIM + z)) = res;
}

extern "C" void kernel_launch(void* const* d_in, const int* in_sizes, int n_in,
                              void* d_out, int out_size, void* d_ws, size_t ws_size,
                              hipStream_t stream) {
    const float* image  = (const float*)d_in[0];   // [2, 96, 128, 128] f32
    const float* angles = (const float*)d_in[1];   // [96] f32
    float* out = (float*)d_out;                    // [2, 128, 128, 128] f32

    const int npix = LDIM * LDIM;                  // 16384 pixels
    dim3 grid(npix / 4);                           // 4096 blocks
    dim3 block(256);
    backproj_kernel<<<grid, block, 0, stream>>>(image, angles, out);
}

// Round 2
// 77.261 us; speedup vs baseline: 1.4215x; 1.4215x over previous
//
#include <hip/hip_runtime.h>
#include <hip/hip_fp16.h>

// Problem constants (fixed by setup_inputs): B=2, N=96, L=128
#define NANG 96
#define LDIM 128
#define NPIX (LDIM * LDIM)                 // 16384
#define IMG_ELEMS (2 * NANG * LDIM * LDIM) // 3,145,728

union H8 { float4 f4; __half2 h2[4]; };

// ---- Pre-pass: image f32 -> f16 into workspace --------------------------
__global__ __launch_bounds__(256)
void convert_f32_to_f16(const float* __restrict__ in, __half* __restrict__ out) {
    const int i = blockIdx.x * 256 + threadIdx.x;  // one thread per 8 elems
    const float4* in4 = (const float4*)in;
    const float4 a = in4[2 * i];
    const float4 b = in4[2 * i + 1];
    H8 u;
    u.h2[0] = __float22half2_rn(make_float2(a.x, a.y));
    u.h2[1] = __float22half2_rn(make_float2(a.z, a.w));
    u.h2[2] = __float22half2_rn(make_float2(b.x, b.y));
    u.h2[3] = __float22half2_rn(make_float2(b.z, b.w));
    ((float4*)out)[i] = u.f4;
}

// ---- Main fp16 backprojection ------------------------------------------
// Block = 256 threads = 4 waves. Block tile: 2 (r) x 4 (q) pixels.
// Wave w owns pixels p = {2w, 2w+1};  p>>2 = dr, p&3 = dq.
// Lane: pxw = lane>>5 (pixel within wave), b = (lane>>4)&1, zo = lane&15,
//       z = zo*8 (8 halfs = 16 B per lane tap load).
__global__ __launch_bounds__(256)
void backproj_f16(const __half* __restrict__ imgh,   // [B, N, L, L] f16
                  const float* __restrict__ angles,  // [N]
                  float* __restrict__ out)           // [B, L, L, L] f32
{
    __shared__ float4 geo[8 * NANG];  // 12 KB: (wA, wB, off0, off1) per (px, angle)

    const int tid = threadIdx.x;
    const int rt = blockIdx.x >> 5;   // 0..63
    const int qt = blockIdx.x & 31;   // 0..31
    const int r0 = rt * 2;
    const int q0 = qt * 4;

    // ---- Phase 1: geometry (8 px x 96 angles), 3 entries/thread ----
    for (int e = tid; e < 8 * NANG; e += 256) {
        const int p = e / NANG;
        const int n = e - p * NANG;
        const int r = r0 + (p >> 2);
        const int q = q0 + (p & 3);

        const float ang = angles[n];
        const float phi = 270.0f - ang;
        const float th  = phi * 0.017453292519943295f;
        float s, c;
        sincosf(th, &s, &c);

        const float xr = (float)q - 63.5f;
        const float yr = (float)r - 63.5f;
        const float sx =  c * xr + s * yr + 63.5f;
        const float sy = -s * xr + c * yr + 63.5f;

        const float x0f = floorf(sx);
        const float y0f = floorf(sy);
        const float wx = sx - x0f;
        const float wy = sy - y0f;
        const int x0 = (int)x0f;
        const int y0 = (int)y0f;

        const float vy0 = (y0 >= 0 && y0 < LDIM)         ? 1.0f : 0.0f;
        const float vy1 = (y0 + 1 >= 0 && y0 + 1 < LDIM) ? 1.0f : 0.0f;
        const float vx0 = (x0 >= 0 && x0 < LDIM)         ? 1.0f : 0.0f;
        const float vx1 = (x0 + 1 >= 0 && x0 + 1 < LDIM) ? 1.0f : 0.0f;

        const float ycomb = vy0 * (1.0f - wy) + vy1 * wy;
        const float wA = (1.0f - wx) * ycomb * vx0;
        const float wB = wx * ycomb * vx1;

        const int xc0 = min(max(x0, 0), LDIM - 1);
        const int xc1 = min(max(x0 + 1, 0), LDIM - 1);

        geo[e] = make_float4(wA, wB,
                             __int_as_float(xc0 * LDIM),
                             __int_as_float(xc1 * LDIM));
    }
    __syncthreads();

    // ---- Phase 2: accumulate over angles ----
    const int w    = tid >> 6;
    const int lane = tid & 63;
    const int pxw  = lane >> 5;
    const int b    = (lane >> 4) & 1;
    const int zo   = lane & 15;
    const int z    = zo * 8;
    const int p    = w * 2 + pxw;
    const int r    = r0 + (p >> 2);
    const int q    = q0 + (p & 3);

    const __half* base = imgh + (size_t)b * (NANG * NPIX) + z;
    const float4* __restrict__ gb = &geo[p * NANG];

    float2 acc[4];
    acc[0] = acc[1] = acc[2] = acc[3] = make_float2(0.f, 0.f);
    float nacc = 0.f;

    #pragma unroll 4
    for (int n = 0; n < NANG; ++n) {
        const float4 g = gb[n];
        const __half* rp = base + n * NPIX;
        H8 u0, u1;
        u0.f4 = *(const float4*)(rp + __float_as_int(g.z));
        u1.f4 = *(const float4*)(rp + __float_as_int(g.w));
        #pragma unroll
        for (int k = 0; k < 4; ++k) {
            const float2 f0 = __half22float2(u0.h2[k]);
            const float2 f1 = __half22float2(u1.h2[k]);
            acc[k].x = fmaf(g.x, f0.x, fmaf(g.y, f1.x, acc[k].x));
            acc[k].y = fmaf(g.x, f0.y, fmaf(g.y, f1.y, acc[k].y));
        }
        nacc += g.x + g.y;
    }

    const float inv = 1.0f / (nacc + 1e-11f);
    const float4 o0 = make_float4(acc[0].x * inv, acc[0].y * inv,
                                  acc[1].x * inv, acc[1].y * inv);
    const float4 o1 = make_float4(acc[2].x * inv, acc[2].y * inv,
                                  acc[3].x * inv, acc[3].y * inv);

    float* op = out + (((size_t)b * LDIM + r) * LDIM + q) * LDIM + z;
    *(float4*)op = o0;
    *(float4*)(op + 4) = o1;
}

// ---- Fallback f32 kernel (proven in R0) if ws can't hold fp16 image ----
__global__ __launch_bounds__(256)
void backproj_f32(const float* __restrict__ image,
                  const float* __restrict__ angles,
                  float* __restrict__ out)
{
    __shared__ float4 geo[4 * NANG];
    const int tid = threadIdx.x;
    const int p0 = blockIdx.x * 4;

    for (int e = tid; e < 4 * NANG; e += 256) {
        const int sub = e / NANG;
        const int n   = e - sub * NANG;
        const int p   = p0 + sub;
        const int r   = p >> 7;
        const int q   = p & 127;
        const float ang = angles[n];
        const float th  = (270.0f - ang) * 0.017453292519943295f;
        float s, c;
        sincosf(th, &s, &c);
        const float xr = (float)q - 63.5f;
        const float yr = (float)r - 63.5f;
        const float sx =  c * xr + s * yr + 63.5f;
        const float sy = -s * xr + c * yr + 63.5f;
        const float x0f = floorf(sx), y0f = floorf(sy);
        const float wx = sx - x0f, wy = sy - y0f;
        const int x0 = (int)x0f, y0 = (int)y0f;
        const float vy0 = (y0 >= 0 && y0 < LDIM) ? 1.0f : 0.0f;
        const float vy1 = (y0 + 1 >= 0 && y0 + 1 < LDIM) ? 1.0f : 0.0f;
        const float vx0 = (x0 >= 0 && x0 < LDIM) ? 1.0f : 0.0f;
        const float vx1 = (x0 + 1 >= 0 && x0 + 1 < LDIM) ? 1.0f : 0.0f;
        const float ycomb = vy0 * (1.0f - wy) + vy1 * wy;
        geo[e] = make_float4((1.0f - wx) * ycomb * vx0, wx * ycomb * vx1,
                             __int_as_float(min(max(x0, 0), LDIM - 1) * LDIM),
                             __int_as_float(min(max(x0 + 1, 0), LDIM - 1) * LDIM));
    }
    __syncthreads();

    const int sub  = tid >> 6;
    const int lane = tid & 63;
    const int b    = lane >> 5;
    const int z    = (lane & 31) * 4;
    const int p    = p0 + sub;
    const int r    = p >> 7;
    const int q    = p & 127;

    const float* imgb = image + (size_t)b * NANG * NPIX + z;
    const float4* __restrict__ gbase = &geo[sub * NANG];
    float4 acc = make_float4(0.f, 0.f, 0.f, 0.f);
    float nacc = 0.f;

    #pragma unroll 4
    for (int n = 0; n < NANG; ++n) {
        const float4 g = gbase[n];
        const float* rowbase = imgb + n * NPIX;
        const float4 v0 = *(const float4*)(rowbase + __float_as_int(g.z));
        const float4 v1 = *(const float4*)(rowbase + __float_as_int(g.w));
        acc.x = fmaf(g.x, v0.x, fmaf(g.y, v1.x, acc.x));
        acc.y = fmaf(g.x, v0.y, fmaf(g.y, v1.y, acc.y));
        acc.z = fmaf(g.x, v0.z, fmaf(g.y, v1.z, acc.z));
        acc.w = fmaf(g.x, v0.w, fmaf(g.y, v1.w, acc.w));
        nacc += g.x + g.y;
    }
    const float inv = 1.0f / (nacc + 1e-11f);
    *(float4*)(out + ((((size_t)b * LDIM + r) * LDIM + q) * LDIM + z)) =
        make_float4(acc.x * inv, acc.y * inv, acc.z * inv, acc.w * inv);
}

extern "C" void kernel_launch(void* const* d_in, const int* in_sizes, int n_in,
                              void* d_out, int out_size, void* d_ws, size_t ws_size,
                              hipStream_t stream) {
    const float* image  = (const float*)d_in[0];   // [2, 96, 128, 128] f32
    const float* angles = (const float*)d_in[1];   // [96] f32
    float* out = (float*)d_out;                    // [2, 128, 128, 128] f32

    const size_t need = (size_t)IMG_ELEMS * sizeof(__half);  // 6.29 MB
    if (ws_size >= need) {
        __half* imgh = (__half*)d_ws;
        convert_f32_to_f16<<<IMG_ELEMS / 8 / 256, 256, 0, stream>>>(image, imgh);
        backproj_f16<<<2048, 256, 0, stream>>>(imgh, angles, out);
    } else {
        backproj_f32<<<NPIX / 4, 256, 0, stream>>>(image, angles, out);
    }
}

// Round 3
// 75.416 us; speedup vs baseline: 1.4563x; 1.0245x over previous
//
#include <hip/hip_runtime.h>
#include <hip/hip_fp16.h>

// Problem constants (fixed by setup_inputs): B=2, N=96, L=128
#define NANG 96
#define LDIM 128
#define NPIX (LDIM * LDIM)                 // 16384
#define IMG_ELEMS (2 * NANG * LDIM * LDIM) // 3,145,728

union H8 { float4 f4; __half2 h2[4]; };

// ---- Pre-pass: f32 [b][n][row][z] -> f16 [n][row][b][z] -----------------
// One tap-row (both b) becomes 512 B contiguous; tap byte offset = (n*128+row)*512.
__global__ __launch_bounds__(256)
void convert_transpose(const float* __restrict__ in, __half* __restrict__ out) {
    const int i = blockIdx.x * 256 + threadIdx.x;  // one thread per 8 elems
    const int rowid = i >> 4;                      // global input row (b,n,row)
    const int zo = i & 15;                         // 8-elem chunk within row
    const int b = rowid / (NANG * LDIM);
    const int rem = rowid - b * (NANG * LDIM);     // n*128 + row

    const float4 a = *(const float4*)(in + (size_t)i * 8);
    const float4 c = *(const float4*)(in + (size_t)i * 8 + 4);
    H8 u;
    u.h2[0] = __float22half2_rn(make_float2(a.x, a.y));
    u.h2[1] = __float22half2_rn(make_float2(a.z, a.w));
    u.h2[2] = __float22half2_rn(make_float2(c.x, c.y));
    u.h2[3] = __float22half2_rn(make_float2(c.z, c.w));
    *(float4*)(out + ((size_t)(rem * 2 + b) * LDIM + zo * 8)) = u.f4;
}

// ---- Main fp16 backprojection ------------------------------------------
// Block = 256 threads = 4 waves; tile = 2 (r) x 4 (q) pixels.
// Wave w owns pixels {2w, 2w+1}. Lane: pxw=lane>>5, b=(lane>>4)&1, zo=lane&15.
// geo holds (wA, wB, byteoff0, byteoff1); tap addr = SGPR base + 32-bit voffset.
__global__ __launch_bounds__(256)
void backproj_f16(const __half* __restrict__ imgh,   // [n][row][b][z] f16
                  const float* __restrict__ angles,  // [N]
                  float* __restrict__ out)           // [B, L, L, L] f32
{
    __shared__ float4 geo[8 * NANG];  // 12 KB

    const int tid = threadIdx.x;
    const int rt = blockIdx.x >> 5;
    const int qt = blockIdx.x & 31;
    const int r0 = rt * 2;
    const int q0 = qt * 4;

    // ---- Phase 1: geometry (8 px x 96 angles) ----
    for (int e = tid; e < 8 * NANG; e += 256) {
        const int p = e / NANG;
        const int n = e - p * NANG;
        const int r = r0 + (p >> 2);
        const int q = q0 + (p & 3);

        float s, c;
        sincosf((270.0f - angles[n]) * 0.017453292519943295f, &s, &c);

        const float xr = (float)q - 63.5f;
        const float yr = (float)r - 63.5f;
        const float sx =  c * xr + s * yr + 63.5f;
        const float sy = -s * xr + c * yr + 63.5f;

        const float x0f = floorf(sx);
        const float y0f = floorf(sy);
        const float wx = sx - x0f;
        const float wy = sy - y0f;
        const int x0 = (int)x0f;
        const int y0 = (int)y0f;

        const float vy0 = (y0 >= 0 && y0 < LDIM)         ? 1.0f : 0.0f;
        const float vy1 = (y0 + 1 >= 0 && y0 + 1 < LDIM) ? 1.0f : 0.0f;
        const float vx0 = (x0 >= 0 && x0 < LDIM)         ? 1.0f : 0.0f;
        const float vx1 = (x0 + 1 >= 0 && x0 + 1 < LDIM) ? 1.0f : 0.0f;

        const float ycomb = vy0 * (1.0f - wy) + vy1 * wy;
        const int xc0 = min(max(x0, 0), LDIM - 1);
        const int xc1 = min(max(x0 + 1, 0), LDIM - 1);

        geo[e] = make_float4((1.0f - wx) * ycomb * vx0,
                             wx * ycomb * vx1,
                             __int_as_float((n * LDIM + xc0) << 9),
                             __int_as_float((n * LDIM + xc1) << 9));
    }
    __syncthreads();

    // ---- Phase 2: accumulate over angles ----
    const int w    = tid >> 6;
    const int lane = tid & 63;
    const int pxw  = lane >> 5;
    const int b    = (lane >> 4) & 1;
    const int zo   = lane & 15;
    const int p    = w * 2 + pxw;
    const int r    = r0 + (p >> 2);
    const int q    = q0 + (p & 3);
    const int laneoff = b * 256 + zo * 16;   // byte offset within 512 B tap-row

    const char* __restrict__ base = (const char*)imgh;
    const float4* __restrict__ gb = &geo[p * NANG];

    float2 acc[4];
    acc[0] = acc[1] = acc[2] = acc[3] = make_float2(0.f, 0.f);
    float nacc = 0.f;

    #pragma unroll 4
    for (int n = 0; n < NANG; ++n) {
        const float4 g = gb[n];
        if (__all(g.x == 0.0f && g.y == 0.0f)) continue;  // whole-wave OOB

        H8 u0, u1;
        u0.f4 = *(const float4*)(base + (__float_as_int(g.z) + laneoff));
        u1.f4 = *(const float4*)(base + (__float_as_int(g.w) + laneoff));

        #pragma unroll
        for (int k = 0; k < 4; ++k) {
            // fmaf(f32, cvt(f16), f32) -> v_fma_mix_f32
            acc[k].x = fmaf(g.x, __half2float(__low2half(u0.h2[k])),  acc[k].x);
            acc[k].x = fmaf(g.y, __half2float(__low2half(u1.h2[k])),  acc[k].x);
            acc[k].y = fmaf(g.x, __half2float(__high2half(u0.h2[k])), acc[k].y);
            acc[k].y = fmaf(g.y, __half2float(__high2half(u1.h2[k])), acc[k].y);
        }
        nacc += g.x + g.y;
    }

    const float inv = 1.0f / (nacc + 1e-11f);
    const float4 o0 = make_float4(acc[0].x * inv, acc[0].y * inv,
                                  acc[1].x * inv, acc[1].y * inv);
    const float4 o1 = make_float4(acc[2].x * inv, acc[2].y * inv,
                                  acc[3].x * inv, acc[3].y * inv);

    float* op = out + (((size_t)b * LDIM + r) * LDIM + q) * LDIM + zo * 8;
    *(float4*)op = o0;
    *(float4*)(op + 4) = o1;
}

// ---- Fallback f32 kernel (proven in R0) if ws can't hold fp16 image ----
__global__ __launch_bounds__(256)
void backproj_f32(const float* __restrict__ image,
                  const float* __restrict__ angles,
                  float* __restrict__ out)
{
    __shared__ float4 geo[4 * NANG];
    const int tid = threadIdx.x;
    const int p0 = blockIdx.x * 4;

    for (int e = tid; e < 4 * NANG; e += 256) {
        const int sub = e / NANG;
        const int n   = e - sub * NANG;
        const int p   = p0 + sub;
        const int r   = p >> 7;
        const int q   = p & 127;
        float s, c;
        sincosf((270.0f - angles[n]) * 0.017453292519943295f, &s, &c);
        const float xr = (float)q - 63.5f;
        const float yr = (float)r - 63.5f;
        const float sx =  c * xr + s * yr + 63.5f;
        const float sy = -s * xr + c * yr + 63.5f;
        const float x0f = floorf(sx), y0f = floorf(sy);
        const float wx = sx - x0f, wy = sy - y0f;
        const int x0 = (int)x0f, y0 = (int)y0f;
        const float vy0 = (y0 >= 0 && y0 < LDIM) ? 1.0f : 0.0f;
        const float vy1 = (y0 + 1 >= 0 && y0 + 1 < LDIM) ? 1.0f : 0.0f;
        const float vx0 = (x0 >= 0 && x0 < LDIM) ? 1.0f : 0.0f;
        const float vx1 = (x0 + 1 >= 0 && x0 + 1 < LDIM) ? 1.0f : 0.0f;
        const float ycomb = vy0 * (1.0f - wy) + vy1 * wy;
        geo[e] = make_float4((1.0f - wx) * ycomb * vx0, wx * ycomb * vx1,
                             __int_as_float(min(max(x0, 0), LDIM - 1) * LDIM),
                             __int_as_float(min(max(x0 + 1, 0), LDIM - 1) * LDIM));
    }
    __syncthreads();

    const int sub  = tid >> 6;
    const int lane = tid & 63;
    const int b    = lane >> 5;
    const int z    = (lane & 31) * 4;
    const int p    = p0 + sub;
    const int r    = p >> 7;
    const int q    = p & 127;

    const float* imgb = image + (size_t)b * NANG * NPIX + z;
    const float4* __restrict__ gbase = &geo[sub * NANG];
    float4 acc = make_float4(0.f, 0.f, 0.f, 0.f);
    float nacc = 0.f;

    #pragma unroll 4
    for (int n = 0; n < NANG; ++n) {
        const float4 g = gbase[n];
        const float* rowbase = imgb + n * NPIX;
        const float4 v0 = *(const float4*)(rowbase + __float_as_int(g.z));
        const float4 v1 = *(const float4*)(rowbase + __float_as_int(g.w));
        acc.x = fmaf(g.x, v0.x, fmaf(g.y, v1.x, acc.x));
        acc.y = fmaf(g.x, v0.y, fmaf(g.y, v1.y, acc.y));
        acc.z = fmaf(g.x, v0.z, fmaf(g.y, v1.z, acc.z));
        acc.w = fmaf(g.x, v0.w, fmaf(g.y, v1.w, acc.w));
        nacc += g.x + g.y;
    }
    const float inv = 1.0f / (nacc + 1e-11f);
    *(float4*)(out + ((((size_t)b * LDIM + r) * LDIM + q) * LDIM + z)) =
        make_float4(acc.x * inv, acc.y * inv, acc.z * inv, acc.w * inv);
}

extern "C" void kernel_launch(void* const* d_in, const int* in_sizes, int n_in,
                              void* d_out, int out_size, void* d_ws, size_t ws_size,
                              hipStream_t stream) {
    const float* image  = (const float*)d_in[0];   // [2, 96, 128, 128] f32
    const float* angles = (const float*)d_in[1];   // [96] f32
    float* out = (float*)d_out;                    // [2, 128, 128, 128] f32

    const size_t need = (size_t)IMG_ELEMS * sizeof(__half);  // 6.29 MB
    if (ws_size >= need) {
        __half* imgh = (__half*)d_ws;
        convert_transpose<<<IMG_ELEMS / 8 / 256, 256, 0, stream>>>(image, imgh);
        backproj_f16<<<2048, 256, 0, stream>>>(imgh, angles, out);
    } else {
        backproj_f32<<<NPIX / 4, 256, 0, stream>>>(image, angles, out);
    }
}

// Round 4
// 71.576 us; speedup vs baseline: 1.5344x; 1.0536x over previous
//
#include <hip/hip_runtime.h>
#include <hip/hip_fp16.h>

// Problem constants (fixed by setup_inputs): B=2, N=96, L=128
#define NANG 96
#define LDIM 128
#define NPIX (LDIM * LDIM)                 // 16384
#define IMG_ELEMS (2 * NANG * LDIM * LDIM) // 3,145,728
#define TPX 16                             // 4x4 pixel tile per block
#define WROWS 8                            // staged source rows per angle
#define ROWB 512                           // bytes per tap-row (2 b x 128 z x fp16)

union H8 { float4 f4; __half2 h2[4]; };

// ---- Pre-pass: f32 [b][n][row][z] -> f16 [n][row][b][z] -----------------
// One tap-row (both b) is 512 B contiguous; row byte offset = (n*128+row)*512.
__global__ __launch_bounds__(256)
void convert_transpose(const float* __restrict__ in, __half* __restrict__ out) {
    const int i = blockIdx.x * 256 + threadIdx.x;  // one thread per 8 elems
    const int rowid = i >> 4;                      // global input row (b,n,row)
    const int zo = i & 15;
    const int b = rowid / (NANG * LDIM);
    const int rem = rowid - b * (NANG * LDIM);     // n*128 + row

    const float4 a = *(const float4*)(in + (size_t)i * 8);
    const float4 c = *(const float4*)(in + (size_t)i * 8 + 4);
    H8 u;
    u.h2[0] = __float22half2_rn(make_float2(a.x, a.y));
    u.h2[1] = __float22half2_rn(make_float2(a.z, a.w));
    u.h2[2] = __float22half2_rn(make_float2(c.x, c.y));
    u.h2[3] = __float22half2_rn(make_float2(c.z, c.w));
    *(float4*)(out + ((size_t)(rem * 2 + b) * LDIM + zo * 8)) = u.f4;
}

// ---- LDS-staged backprojection ------------------------------------------
// Block = 256 threads = 4 waves; tile = 4 (r) x 4 (q) = 16 pixels.
// Per angle: stage 8 source rows (4 KB) into dbuf LDS, serve 16 px x 2 taps
// from LDS. Lane: pxw=lane>>5, b=(lane>>4)&1, zo=lane&15 (8 halfs per lane).
__global__ __launch_bounds__(256)
void backproj_lds(const __half* __restrict__ imgh,   // [n][row][b][z] f16
                  const float* __restrict__ angles,  // [N]
                  float* __restrict__ out)           // [B, L, L, L] f32
{
    __shared__ float4 geo[TPX][NANG];                 // 24576 B
    __shared__ float4 smeta[NANG];                    // 1536 B (s, c, slo, gbyte)
    __shared__ __align__(16) char stage[2][WROWS * ROWB]; // 8192 B

    const int tid = threadIdx.x;
    const int rt = blockIdx.x >> 5;    // 0..31
    const int qt = blockIdx.x & 31;    // 0..31
    const int r0 = rt * 4;
    const int q0 = qt * 4;

    // ---- Phase 0: per-angle meta (sincos + staging window) ----
    if (tid < NANG) {
        float s, c;
        sincosf((270.0f - angles[tid]) * 0.017453292519943295f, &s, &c);
        const float xrl = (float)q0 - 63.5f, xrh = xrl + 3.0f;
        const float yrl = (float)r0 - 63.5f, yrh = yrl + 3.0f;
        const float mn = fminf(c * xrl, c * xrh) + fminf(s * yrl, s * yrh) + 63.5f;
        const int lo = (int)floorf(mn);
        const int slo = min(max(lo, 0), LDIM - WROWS);
        smeta[tid] = make_float4(s, c, __int_as_float(slo),
                                 __int_as_float((tid * LDIM + slo) << 9));
    }
    __syncthreads();

    // ---- Phase 1: geometry for 16 px x 96 angles (window-relative) ----
    for (int e = tid; e < TPX * NANG; e += 256) {
        const int px = e / NANG;
        const int n  = e - px * NANG;
        const float4 m = smeta[n];
        const float s = m.x, c = m.y;
        const int slo = __float_as_int(m.z);

        const float xr = (float)(q0 + (px & 3)) - 63.5f;
        const float yr = (float)(r0 + (px >> 2)) - 63.5f;
        const float sx =  c * xr + s * yr + 63.5f;
        const float sy = -s * xr + c * yr + 63.5f;

        const float x0f = floorf(sx), y0f = floorf(sy);
        const float wx = sx - x0f, wy = sy - y0f;
        const int x0 = (int)x0f, y0 = (int)y0f;

        const float vy0 = (y0 >= 0 && y0 < LDIM)         ? 1.0f : 0.0f;
        const float vy1 = (y0 + 1 >= 0 && y0 + 1 < LDIM) ? 1.0f : 0.0f;
        const float vx0 = (x0 >= 0 && x0 < LDIM)         ? 1.0f : 0.0f;
        const float vx1 = (x0 + 1 >= 0 && x0 + 1 < LDIM) ? 1.0f : 0.0f;
        const float ycomb = vy0 * (1.0f - wy) + vy1 * wy;

        // window-relative row offsets, clamped (clamp only binds in the
        // floor-ulp edge case where the tap weight ~0)
        const int offA = min(max(min(max(x0, 0), LDIM - 1) - slo, 0), WROWS - 1);
        const int offB = min(max(min(max(x0 + 1, 0), LDIM - 1) - slo, 0), WROWS - 1);

        geo[px][n] = make_float4((1.0f - wx) * ycomb * vx0,
                                 wx * ycomb * vx1,
                                 __int_as_float(offA << 9),
                                 __int_as_float(offB << 9));
    }

    const int wv   = tid >> 6;
    const int lane = tid & 63;
    const int pxw  = lane >> 5;
    const int b    = (lane >> 4) & 1;
    const int zo   = lane & 15;
    const int laneoff = b * 256 + zo * 16;   // byte offset within 512 B row

    // stage(a): 256 threads x 16 B = 4 KB window, contiguous in global.
    auto issue_stage = [&](int a, int bufsel) {
        const int gb = __float_as_int(smeta[a].w);
        const char* gp = (const char*)imgh + gb + tid * 16;
        char* lp = &stage[bufsel][0] + (tid & 0xC0) * 16;  // wave-uniform base
        __builtin_amdgcn_global_load_lds(
            (const __attribute__((address_space(1))) void*)gp,
            (__attribute__((address_space(3))) void*)lp, 16, 0, 0);
    };

    float2 acc[2][4] = {};
    float nacc[2] = {0.f, 0.f};

    auto compute = [&](int a, int bufsel) {
        const char* sb = &stage[bufsel][0];
        #pragma unroll
        for (int pass = 0; pass < 2; ++pass) {
            const int px = pass * 8 + wv * 2 + pxw;
            const float4 g = geo[px][a];
            H8 u0, u1;
            u0.f4 = *(const float4*)(sb + (__float_as_int(g.z) + laneoff));
            u1.f4 = *(const float4*)(sb + (__float_as_int(g.w) + laneoff));
            #pragma unroll
            for (int k = 0; k < 4; ++k) {
                acc[pass][k].x = fmaf(g.x, __half2float(__low2half(u0.h2[k])),  acc[pass][k].x);
                acc[pass][k].x = fmaf(g.y, __half2float(__low2half(u1.h2[k])),  acc[pass][k].x);
                acc[pass][k].y = fmaf(g.x, __half2float(__high2half(u0.h2[k])), acc[pass][k].y);
                acc[pass][k].y = fmaf(g.y, __half2float(__high2half(u1.h2[k])), acc[pass][k].y);
            }
            nacc[pass] += g.x + g.y;
        }
    };

    issue_stage(0, 0);
    for (int a = 0; a < NANG; a += 2) {
        asm volatile("s_waitcnt vmcnt(0)" ::: "memory");
        __syncthreads();                       // stage(a) landed, prev compute done
        issue_stage(a + 1, 1);                 // prefetch next angle
        compute(a, 0);
        asm volatile("s_waitcnt vmcnt(0)" ::: "memory");
        __syncthreads();
        if (a + 2 < NANG) issue_stage(a + 2, 0);
        compute(a + 1, 1);
    }

    // ---- Epilogue ----
    #pragma unroll
    for (int pass = 0; pass < 2; ++pass) {
        const int px = pass * 8 + wv * 2 + pxw;
        const int r = r0 + (px >> 2);
        const int q = q0 + (px & 3);
        const float inv = 1.0f / (nacc[pass] + 1e-11f);
        float* op = out + ((((size_t)b * LDIM + r) * LDIM + q) * LDIM + zo * 8);
        *(float4*)op     = make_float4(acc[pass][0].x * inv, acc[pass][0].y * inv,
                                       acc[pass][1].x * inv, acc[pass][1].y * inv);
        *(float4*)(op+4) = make_float4(acc[pass][2].x * inv, acc[pass][2].y * inv,
                                       acc[pass][3].x * inv, acc[pass][3].y * inv);
    }
}

// ---- Fallback f32 kernel (proven in R0) if ws can't hold fp16 image ----
__global__ __launch_bounds__(256)
void backproj_f32(const float* __restrict__ image,
                  const float* __restrict__ angles,
                  float* __restrict__ out)
{
    __shared__ float4 geo[4 * NANG];
    const int tid = threadIdx.x;
    const int p0 = blockIdx.x * 4;

    for (int e = tid; e < 4 * NANG; e += 256) {
        const int sub = e / NANG;
        const int n   = e - sub * NANG;
        const int p   = p0 + sub;
        const int r   = p >> 7;
        const int q   = p & 127;
        float s, c;
        sincosf((270.0f - angles[n]) * 0.017453292519943295f, &s, &c);
        const float xr = (float)q - 63.5f;
        const float yr = (float)r - 63.5f;
        const float sx =  c * xr + s * yr + 63.5f;
        const float sy = -s * xr + c * yr + 63.5f;
        const float x0f = floorf(sx), y0f = floorf(sy);
        const float wx = sx - x0f, wy = sy - y0f;
        const int x0 = (int)x0f, y0 = (int)y0f;
        const float vy0 = (y0 >= 0 && y0 < LDIM) ? 1.0f : 0.0f;
        const float vy1 = (y0 + 1 >= 0 && y0 + 1 < LDIM) ? 1.0f : 0.0f;
        const float vx0 = (x0 >= 0 && x0 < LDIM) ? 1.0f : 0.0f;
        const float vx1 = (x0 + 1 >= 0 && x0 + 1 < LDIM) ? 1.0f : 0.0f;
        const float ycomb = vy0 * (1.0f - wy) + vy1 * wy;
        geo[e] = make_float4((1.0f - wx) * ycomb * vx0, wx * ycomb * vx1,
                             __int_as_float(min(max(x0, 0), LDIM - 1) * LDIM),
                             __int_as_float(min(max(x0 + 1, 0), LDIM - 1) * LDIM));
    }
    __syncthreads();

    const int sub  = tid >> 6;
    const int lane = tid & 63;
    const int b    = lane >> 5;
    const int z    = (lane & 31) * 4;
    const int p    = p0 + sub;
    const int r    = p >> 7;
    const int q    = p & 127;

    const float* imgb = image + (size_t)b * NANG * NPIX + z;
    const float4* __restrict__ gbase = &geo[sub * NANG];
    float4 acc = make_float4(0.f, 0.f, 0.f, 0.f);
    float nacc = 0.f;

    #pragma unroll 4
    for (int n = 0; n < NANG; ++n) {
        const float4 g = gbase[n];
        const float* rowbase = imgb + n * NPIX;
        const float4 v0 = *(const float4*)(rowbase + __float_as_int(g.z));
        const float4 v1 = *(const float4*)(rowbase + __float_as_int(g.w));
        acc.x = fmaf(g.x, v0.x, fmaf(g.y, v1.x, acc.x));
        acc.y = fmaf(g.x, v0.y, fmaf(g.y, v1.y, acc.y));
        acc.z = fmaf(g.x, v0.z, fmaf(g.y, v1.z, acc.z));
        acc.w = fmaf(g.x, v0.w, fmaf(g.y, v1.w, acc.w));
        nacc += g.x + g.y;
    }
    const float inv = 1.0f / (nacc + 1e-11f);
    *(float4*)(out + ((((size_t)b * LDIM + r) * LDIM + q) * LDIM + z)) =
        make_float4(acc.x * inv, acc.y * inv, acc.z * inv, acc.w * inv);
}

extern "C" void kernel_launch(void* const* d_in, const int* in_sizes, int n_in,
                              void* d_out, int out_size, void* d_ws, size_t ws_size,
                              hipStream_t stream) {
    const float* image  = (const float*)d_in[0];   // [2, 96, 128, 128] f32
    const float* angles = (const float*)d_in[1];   // [96] f32
    float* out = (float*)d_out;                    // [2, 128, 128, 128] f32

    const size_t need = (size_t)IMG_ELEMS * sizeof(__half);  // 6.29 MB
    if (ws_size >= need) {
        __half* imgh = (__half*)d_ws;
        convert_transpose<<<IMG_ELEMS / 8 / 256, 256, 0, stream>>>(image, imgh);
        backproj_lds<<<1024, 256, 0, stream>>>(imgh, angles, out);
    } else {
        backproj_f32<<<NPIX / 4, 256, 0, stream>>>(image, angles, out);
    }
}

// Round 5
// 69.053 us; speedup vs baseline: 1.5905x; 1.0365x over previous
//
#include <hip/hip_runtime.h>
#include <hip/hip_fp16.h>

// Problem constants (fixed by setup_inputs): B=2, N=96, L=128
#define NANG 96
#define LDIM 128
#define NPIX (LDIM * LDIM)                 // 16384
#define IMG_ELEMS (2 * NANG * LDIM * LDIM) // 3,145,728
#define TPX 16                             // 4x4 pixel tile per block
#define WROWS 8                            // staged source rows per angle
#define ROWB 512                           // bytes per tap-row (2 b x 128 z x fp16)

union H8 { float4 f4; __half2 h2[4]; };
union HU { unsigned int u; __half2 h; };

// ---- Pre-pass: f32 [b][n][row][z] -> f16 [n][row][b][z] -----------------
// One tap-row (both b) is 512 B contiguous; row byte offset = (n*128+row)*512.
__global__ __launch_bounds__(256)
void convert_transpose(const float* __restrict__ in, __half* __restrict__ out) {
    const int i = blockIdx.x * 256 + threadIdx.x;  // one thread per 8 elems
    const int rowid = i >> 4;                      // global input row (b,n,row)
    const int zo = i & 15;
    const int b = rowid / (NANG * LDIM);
    const int rem = rowid - b * (NANG * LDIM);     // n*128 + row

    const float4 a = *(const float4*)(in + (size_t)i * 8);
    const float4 c = *(const float4*)(in + (size_t)i * 8 + 4);
    H8 u;
    u.h2[0] = __float22half2_rn(make_float2(a.x, a.y));
    u.h2[1] = __float22half2_rn(make_float2(a.z, a.w));
    u.h2[2] = __float22half2_rn(make_float2(c.x, c.y));
    u.h2[3] = __float22half2_rn(make_float2(c.z, c.w));
    *(float4*)(out + ((size_t)(rem * 2 + b) * LDIM + zo * 8)) = u.f4;
}

// ---- LDS-staged fp16-packed backprojection ------------------------------
// Block = 256 threads = 4 waves; tile = 4 (r) x 4 (q) = 16 pixels.
// Per angle: stage 8 source rows (4 KB) into dbuf LDS via global_load_lds,
// serve 16 px x 2 taps from LDS with v_pk_fma_f16 (fp16 accumulators).
// Lane: pxw=lane>>5, b=(lane>>4)&1, zo=lane&15 (8 halfs per lane).
__global__ __launch_bounds__(256)
void backproj_lds(const __half* __restrict__ imgh,   // [n][row][b][z] f16
                  const float* __restrict__ angles,  // [N]
                  float* __restrict__ out)           // [B, L, L, L] f32
{
    __shared__ float4 geo[TPX][NANG];                 // 24576 B: (wA2, wB2, offA, offB)
    __shared__ float4 smeta[NANG];                    // 1536 B (s, c, slo, gbyte)
    __shared__ float  snorm[TPX];                     // 64 B
    __shared__ __align__(16) char stage[2][WROWS * ROWB]; // 8192 B

    const int tid = threadIdx.x;
    const int rt = blockIdx.x >> 5;    // 0..31
    const int qt = blockIdx.x & 31;    // 0..31
    const int r0 = rt * 4;
    const int q0 = qt * 4;

    // ---- Phase 0: per-angle meta (sincos + staging window) ----
    if (tid < NANG) {
        float s, c;
        sincosf((270.0f - angles[tid]) * 0.017453292519943295f, &s, &c);
        const float xrl = (float)q0 - 63.5f, xrh = xrl + 3.0f;
        const float yrl = (float)r0 - 63.5f, yrh = yrl + 3.0f;
        const float mn = fminf(c * xrl, c * xrh) + fminf(s * yrl, s * yrh) + 63.5f;
        const int lo = (int)floorf(mn);
        const int slo = min(max(lo, 0), LDIM - WROWS);
        smeta[tid] = make_float4(s, c, __int_as_float(slo),
                                 __int_as_float((tid * LDIM + slo) << 9));
    }
    if (tid < TPX) snorm[tid] = 0.0f;
    __syncthreads();

    // ---- Phase 1: geometry (16 px x 96 angles), weights packed as half2 ----
    for (int e = tid; e < TPX * NANG; e += 256) {
        const int px = e / NANG;
        const int n  = e - px * NANG;
        const float4 m = smeta[n];
        const float s = m.x, c = m.y;
        const int slo = __float_as_int(m.z);

        const float xr = (float)(q0 + (px & 3)) - 63.5f;
        const float yr = (float)(r0 + (px >> 2)) - 63.5f;
        const float sx =  c * xr + s * yr + 63.5f;
        const float sy = -s * xr + c * yr + 63.5f;

        const float x0f = floorf(sx), y0f = floorf(sy);
        const float wx = sx - x0f, wy = sy - y0f;
        const int x0 = (int)x0f, y0 = (int)y0f;

        const float vy0 = (y0 >= 0 && y0 < LDIM)         ? 1.0f : 0.0f;
        const float vy1 = (y0 + 1 >= 0 && y0 + 1 < LDIM) ? 1.0f : 0.0f;
        const float vx0 = (x0 >= 0 && x0 < LDIM)         ? 1.0f : 0.0f;
        const float vx1 = (x0 + 1 >= 0 && x0 + 1 < LDIM) ? 1.0f : 0.0f;
        const float ycomb = vy0 * (1.0f - wy) + vy1 * wy;

        const float wA = (1.0f - wx) * ycomb * vx0;
        const float wB = wx * ycomb * vx1;

        // window-relative row offsets, clamped (clamp only binds when the
        // corresponding weight ~0)
        const int offA = min(max(min(max(x0, 0), LDIM - 1) - slo, 0), WROWS - 1);
        const int offB = min(max(min(max(x0 + 1, 0), LDIM - 1) - slo, 0), WROWS - 1);

        HU ha, hb;
        ha.h = __float2half2_rn(wA);   // broadcast pair (wA, wA)
        hb.h = __float2half2_rn(wB);

        geo[px][n] = make_float4(__uint_as_float(ha.u),
                                 __uint_as_float(hb.u),
                                 __int_as_float(offA << 9),
                                 __int_as_float(offB << 9));
        atomicAdd(&snorm[px], wA + wB);   // norm is data-independent
    }

    const int wv   = tid >> 6;
    const int lane = tid & 63;
    const int pxw  = lane >> 5;
    const int b    = (lane >> 4) & 1;
    const int zo   = lane & 15;
    const int laneoff = b * 256 + zo * 16;   // byte offset within 512 B row

    // stage(a): 256 threads x 16 B = 4 KB window, contiguous in global.
    auto issue_stage = [&](int a, int bufsel) {
        const int gb = __float_as_int(smeta[a].w);
        const char* gp = (const char*)imgh + gb + tid * 16;
        char* lp = &stage[bufsel][0] + (tid & 0xC0) * 16;  // wave-uniform base
        __builtin_amdgcn_global_load_lds(
            (const __attribute__((address_space(1))) void*)gp,
            (__attribute__((address_space(3))) void*)lp, 16, 0, 0);
    };

    __half2 acc[2][4] = {};

    auto compute = [&](int a, int bufsel) {
        const char* sb = &stage[bufsel][0];
        #pragma unroll
        for (int pass = 0; pass < 2; ++pass) {
            const int px = pass * 8 + wv * 2 + pxw;
            const float4 g = geo[px][a];
            HU wa, wb;
            wa.u = __float_as_uint(g.x);
            wb.u = __float_as_uint(g.y);
            H8 u0, u1;
            u0.f4 = *(const float4*)(sb + (__float_as_int(g.z) + laneoff));
            u1.f4 = *(const float4*)(sb + (__float_as_int(g.w) + laneoff));
            #pragma unroll
            for (int k = 0; k < 4; ++k) {
                acc[pass][k] = __hfma2(wa.h, u0.h2[k], acc[pass][k]);
                acc[pass][k] = __hfma2(wb.h, u1.h2[k], acc[pass][k]);
            }
        }
    };

    issue_stage(0, 0);
    for (int a = 0; a < NANG; a += 2) {
        asm volatile("s_waitcnt vmcnt(0)" ::: "memory");
        __syncthreads();                       // stage(a) landed, prev compute done
        issue_stage(a + 1, 1);                 // prefetch next angle
        compute(a, 0);
        asm volatile("s_waitcnt vmcnt(0)" ::: "memory");
        __syncthreads();
        if (a + 2 < NANG) issue_stage(a + 2, 0);
        compute(a + 1, 1);
    }

    // ---- Epilogue: fp16 acc -> f32, divide by precomputed norm ----
    #pragma unroll
    for (int pass = 0; pass < 2; ++pass) {
        const int px = pass * 8 + wv * 2 + pxw;
        const int r = r0 + (px >> 2);
        const int q = q0 + (px & 3);
        const float inv = 1.0f / (snorm[px] + 1e-11f);
        const float2 f0 = __half22float2(acc[pass][0]);
        const float2 f1 = __half22float2(acc[pass][1]);
        const float2 f2 = __half22float2(acc[pass][2]);
        const float2 f3 = __half22float2(acc[pass][3]);
        float* op = out + ((((size_t)b * LDIM + r) * LDIM + q) * LDIM + zo * 8);
        *(float4*)op     = make_float4(f0.x * inv, f0.y * inv, f1.x * inv, f1.y * inv);
        *(float4*)(op+4) = make_float4(f2.x * inv, f2.y * inv, f3.x * inv, f3.y * inv);
    }
}

// ---- Fallback f32 kernel (proven in R0) if ws can't hold fp16 image ----
__global__ __launch_bounds__(256)
void backproj_f32(const float* __restrict__ image,
                  const float* __restrict__ angles,
                  float* __restrict__ out)
{
    __shared__ float4 geo[4 * NANG];
    const int tid = threadIdx.x;
    const int p0 = blockIdx.x * 4;

    for (int e = tid; e < 4 * NANG; e += 256) {
        const int sub = e / NANG;
        const int n   = e - sub * NANG;
        const int p   = p0 + sub;
        const int r   = p >> 7;
        const int q   = p & 127;
        float s, c;
        sincosf((270.0f - angles[n]) * 0.017453292519943295f, &s, &c);
        const float xr = (float)q - 63.5f;
        const float yr = (float)r - 63.5f;
        const float sx =  c * xr + s * yr + 63.5f;
        const float sy = -s * xr + c * yr + 63.5f;
        const float x0f = floorf(sx), y0f = floorf(sy);
        const float wx = sx - x0f, wy = sy - y0f;
        const int x0 = (int)x0f, y0 = (int)y0f;
        const float vy0 = (y0 >= 0 && y0 < LDIM) ? 1.0f : 0.0f;
        const float vy1 = (y0 + 1 >= 0 && y0 + 1 < LDIM) ? 1.0f : 0.0f;
        const float vx0 = (x0 >= 0 && x0 < LDIM) ? 1.0f : 0.0f;
        const float vx1 = (x0 + 1 >= 0 && x0 + 1 < LDIM) ? 1.0f : 0.0f;
        const float ycomb = vy0 * (1.0f - wy) + vy1 * wy;
        geo[e] = make_float4((1.0f - wx) * ycomb * vx0, wx * ycomb * vx1,
                             __int_as_float(min(max(x0, 0), LDIM - 1) * LDIM),
                             __int_as_float(min(max(x0 + 1, 0), LDIM - 1) * LDIM));
    }
    __syncthreads();

    const int sub  = tid >> 6;
    const int lane = tid & 63;
    const int b    = lane >> 5;
    const int z    = (lane & 31) * 4;
    const int p    = p0 + sub;
    const int r    = p >> 7;
    const int q    = p & 127;

    const float* imgb = image + (size_t)b * NANG * NPIX + z;
    const float4* __restrict__ gbase = &geo[sub * NANG];
    float4 acc = make_float4(0.f, 0.f, 0.f, 0.f);
    float nacc = 0.f;

    #pragma unroll 4
    for (int n = 0; n < NANG; ++n) {
        const float4 g = gbase[n];
        const float* rowbase = imgb + n * NPIX;
        const float4 v0 = *(const float4*)(rowbase + __float_as_int(g.z));
        const float4 v1 = *(const float4*)(rowbase + __float_as_int(g.w));
        acc.x = fmaf(g.x, v0.x, fmaf(g.y, v1.x, acc.x));
        acc.y = fmaf(g.x, v0.y, fmaf(g.y, v1.y, acc.y));
        acc.z = fmaf(g.x, v0.z, fmaf(g.y, v1.z, acc.z));
        acc.w = fmaf(g.x, v0.w, fmaf(g.y, v1.w, acc.w));
        nacc += g.x + g.y;
    }
    const float inv = 1.0f / (nacc + 1e-11f);
    *(float4*)(out + ((((size_t)b * LDIM + r) * LDIM + q) * LDIM + z)) =
        make_float4(acc.x * inv, acc.y * inv, acc.z * inv, acc.w * inv);
}

extern "C" void kernel_launch(void* const* d_in, const int* in_sizes, int n_in,
                              void* d_out, int out_size, void* d_ws, size_t ws_size,
                              hipStream_t stream) {
    const float* image  = (const float*)d_in[0];   // [2, 96, 128, 128] f32
    const float* angles = (const float*)d_in[1];   // [96] f32
    float* out = (float*)d_out;                    // [2, 128, 128, 128] f32

    const size_t need = (size_t)IMG_ELEMS * sizeof(__half);  // 6.29 MB
    if (ws_size >= need) {
        __half* imgh = (__half*)d_ws;
        convert_transpose<<<IMG_ELEMS / 8 / 256, 256, 0, stream>>>(image, imgh);
        backproj_lds<<<1024, 256, 0, stream>>>(imgh, angles, out);
    } else {
        backproj_f32<<<NPIX / 4, 256, 0, stream>>>(image, angles, out);
    }
}